// Round 10
// baseline (1488.397 us; speedup 1.0000x reference)
//
#include <hip/hip_runtime.h>

typedef float f4 __attribute__((ext_vector_type(4)));

#define LENT 998
#define NSAMP 63872   // 64 * 998

// ---------------------------------------------------------------------------
// R10: scalar-weight, sample-per-lane. No LDS, no shuffles, no barriers.
// Wave-uniform weights ride the free SGPR operand of v_fma (1 scalar read
// per VALU instr is architectural); the 16x LDS broadcast amplification that
// bounded R8/R9 disappears. Wave = (b, t-chunk, l) via readfirstlane (forces
// LLVM uniformity -> s_load); lane = t within chunk. 8192 waves, ~8/CU
// resident (VGPR-capped). p0/p1/dt1 register arrays; h,d recomputed from p
// (exact fp32 masks, precision identical to R8/R9's passing config).
// ---------------------------------------------------------------------------
__global__ __launch_bounds__(256, 2) void mlp_sgpr(
    const float* __restrict__ xp,  const float* __restrict__ embp,
    const float* __restrict__ gW0, const float* __restrict__ gb0,
    const float* __restrict__ gW1, const float* __restrict__ gb1,
    const float* __restrict__ gW2, const float* __restrict__ gb2,
    const float* __restrict__ gW3, const float* __restrict__ gb3,
    float* __restrict__ out)
{
    const int tid  = threadIdx.x;
    const int lane = tid & 63;
    // wave id, forced wave-uniform so all weight addresses scalarize
    const int wv   = __builtin_amdgcn_readfirstlane((int)blockIdx.x * 4 + (tid >> 6));
    const int l    = wv & 7;
    const int b    = (wv >> 3) & 63;
    const int tc   = wv >> 9;                    // 0..15
    const int t    = tc * 64 + lane;             // 16*64 = 1024 covers 998
    const int tcl  = t < LENT ? t : LENT - 1;
    const bool act = (t < LENT);

    const float* W0l = gW0 + (size_t)l * 64 * 17;    // uniform base
    const float* W1l = gW1 + (size_t)l * 4096;
    const float* W2l = gW2 + (size_t)l * 4096;

    // per-lane embedding row (t-dependent) and x value
    f4 em[4];
#pragma unroll
    for (int i = 0; i < 4; ++i) em[i] = *(const f4*)(embp + (tcl + 2) * 16 + i * 4);
    const float xv = xp[(size_t)b * 8000 + (size_t)(tcl + 2) * 8 + l];

    // ---- layer 0: p0[k] = b0[k] + W0[k,:16]@emb + W0[k,16]*x  (regs) ----
    float p0[64];
#pragma unroll
    for (int k = 0; k < 64; ++k) {
        const float* r = W0l + k * 17;           // uniform -> s_load
        float acc = gb0[l * 64 + k];             // uniform -> s_load
#pragma unroll
        for (int i = 0; i < 4; ++i) {
            f4 w = *(const f4*)(r + i * 4);      // s_load_dwordx4
            acc = fmaf(w.x, em[i].x, acc);
            acc = fmaf(w.y, em[i].y, acc);
            acc = fmaf(w.z, em[i].z, acc);
            acc = fmaf(w.w, em[i].w, acc);
        }
        p0[k] = fmaf(r[16], xv, acc);
    }

    // ---- layer 1: p1 = W1 @ h0 + b1 ; dt1 = W1 @ d0   (h0,d0 on the fly) ----
    float p1[64], dt1[64];
#pragma unroll
    for (int jc = 0; jc < 4; ++jc) {
        float a[16], d[16];
#pragma unroll
        for (int jj = 0; jj < 16; ++jj) { a[jj] = 0.f; d[jj] = 0.f; }
#pragma unroll
        for (int k4 = 0; k4 < 16; ++k4) {
            float h0v[4], d0v[4];
#pragma unroll
            for (int ki = 0; ki < 4; ++ki) {
                const int k = k4 * 4 + ki;
                float p  = p0[k];
                float m  = (p >= 0.f) ? 1.f : 0.2f;
                float w0 = W0l[k * 17 + 16];     // uniform scalar
                h0v[ki] = p * m;
                d0v[ki] = w0 * m;
            }
#pragma unroll
            for (int jj = 0; jj < 16; ++jj) {
                f4 w = *(const f4*)(W1l + (jc * 16 + jj) * 64 + k4 * 4);  // s_load
                a[jj] = fmaf(w.x, h0v[0], a[jj]);
                a[jj] = fmaf(w.y, h0v[1], a[jj]);
                a[jj] = fmaf(w.z, h0v[2], a[jj]);
                a[jj] = fmaf(w.w, h0v[3], a[jj]);
                d[jj] = fmaf(w.x, d0v[0], d[jj]);
                d[jj] = fmaf(w.y, d0v[1], d[jj]);
                d[jj] = fmaf(w.z, d0v[2], d[jj]);
                d[jj] = fmaf(w.w, d0v[3], d[jj]);
            }
        }
#pragma unroll
        for (int jj = 0; jj < 16; ++jj) {
            p1[jc * 16 + jj]  = a[jj] + gb1[l * 64 + jc * 16 + jj];
            dt1[jc * 16 + jj] = d[jj];
        }
    }

    // ---- layer 2 + layer 3 fused: h1,dh1 recomputed from p1,dt1 ----
    float rs = 0.f, js = 0.f;
#pragma unroll
    for (int jc = 0; jc < 4; ++jc) {
        float a[16], d[16];
#pragma unroll
        for (int jj = 0; jj < 16; ++jj) { a[jj] = 0.f; d[jj] = 0.f; }
#pragma unroll
        for (int k4 = 0; k4 < 16; ++k4) {
            float h1v[4], d1v[4];
#pragma unroll
            for (int ki = 0; ki < 4; ++ki) {
                const int k = k4 * 4 + ki;
                float p = p1[k];
                float m = (p >= 0.f) ? 1.f : 0.2f;
                h1v[ki] = p * m;
                d1v[ki] = dt1[k] * m;
            }
#pragma unroll
            for (int jj = 0; jj < 16; ++jj) {
                f4 w = *(const f4*)(W2l + (jc * 16 + jj) * 64 + k4 * 4);  // s_load
                a[jj] = fmaf(w.x, h1v[0], a[jj]);
                a[jj] = fmaf(w.y, h1v[1], a[jj]);
                a[jj] = fmaf(w.z, h1v[2], a[jj]);
                a[jj] = fmaf(w.w, h1v[3], a[jj]);
                d[jj] = fmaf(w.x, d1v[0], d[jj]);
                d[jj] = fmaf(w.y, d1v[1], d[jj]);
                d[jj] = fmaf(w.z, d1v[2], d[jj]);
                d[jj] = fmaf(w.w, d1v[3], d[jj]);
            }
        }
#pragma unroll
        for (int jj = 0; jj < 16; ++jj) {
            float p  = a[jj] + gb2[l * 64 + jc * 16 + jj];
            float w3 = gW3[l * 64 + jc * 16 + jj];
            float m  = (p >= 0.f) ? 1.f : 0.2f;
            rs = fmaf(w3, p * m, rs);
            js = fmaf(w3, d[jj] * m, js);
        }
    }
    rs += gb3[l];

    if (act) {
        out[((size_t)b * LENT + t) * 8 + l] = rs;
        atomicAdd(&out[(size_t)NSAMP * 8 + (size_t)b * LENT + t], __logf(fabsf(js)));
    }
}

extern "C" void kernel_launch(void* const* d_in, const int* in_sizes, int n_in,
                              void* d_out, int out_size, void* d_ws, size_t ws_size,
                              hipStream_t stream) {
    (void)in_sizes; (void)n_in; (void)out_size; (void)d_ws; (void)ws_size;
    // zero logdet region (accumulated via atomicAdd across l-waves)
    hipMemsetAsync((char*)d_out + (size_t)NSAMP * 8 * sizeof(float), 0,
                   (size_t)NSAMP * sizeof(float), stream);
    mlp_sgpr<<<dim3(2048), 256, 0, stream>>>(
        (const float*)d_in[0], (const float*)d_in[1],
        (const float*)d_in[2], (const float*)d_in[3],
        (const float*)d_in[4], (const float*)d_in[5],
        (const float*)d_in[6], (const float*)d_in[7],
        (const float*)d_in[8], (const float*)d_in[9],
        (float*)d_out);
}

// Round 12
// 193.850 us; speedup vs baseline: 7.6781x; 7.6781x over previous
//
#include <hip/hip_runtime.h>

typedef unsigned short u16;
typedef float f32x4 __attribute__((ext_vector_type(4)));
typedef short short8 __attribute__((ext_vector_type(8)));
typedef unsigned int uint2v __attribute__((ext_vector_type(2)));
typedef unsigned int uint4v __attribute__((ext_vector_type(4)));

#define STRW 72           // u16 stride for weight tiles (144B rows, 16B-aligned)
#define STRU 36           // uint stride for per-wave scratch (144B rows)
#define LENT 998
#define NSAMP 63872       // 64 * 998

#define LDSFENCE() asm volatile("s_waitcnt lgkmcnt(0)" ::: "memory")

// round to bf16, result as fp32-bit-pattern (low 16 bits zero)
static __device__ __forceinline__ unsigned int rndbf(float v) {
    return (__builtin_bit_cast(unsigned int, v) + 0x8000u) & 0xFFFF0000u;
}
// 3-term split: v = f(a)+f(b)+f(c) + O(2^-25 v). r1,r2 subtractions are exact.
static __device__ __forceinline__ void split3(float v, unsigned int& a,
                                              unsigned int& b, unsigned int& c) {
    a = rndbf(v);
    float r1 = v - __builtin_bit_cast(float, a);
    b = rndbf(r1);
    float r2 = r1 - __builtin_bit_cast(float, b);
    c = rndbf(r2);
}
// pack two bf16 (fp32-bit patterns) into one dword; low16 = x
static __device__ __forceinline__ unsigned int packb(unsigned int x, unsigned int y) {
    return (x >> 16) | (y & 0xFFFF0000u);
}

// ---------------------------------------------------------------------------
// R12: 3-term-split bf16 MFMA (fp32-equivalent accuracy, ~2^-24).
// R11 (2-term, 2^-16) gave logdet 2.75; fp32 VALU (R8) passed at 0.25 -> the
// required accuracy is fp32-grade. 6 MFMAs per GEMM keep all product terms
// >= 2^-24: wh*Hh + (wh*Hm + wm*Hh) + (wh*Hl + wm*Hm + wl*Hh).
// Block = one (t,l), 256 thr = 4 waves x 16 samples; grid (998,8).
// Frag layouts / transform / outputs inherited from R5/R11 (residuals
// verified twice). Single barrier; waves then run barrier-free with
// per-wave scratch (in-wave lgkmcnt fences only).
// ---------------------------------------------------------------------------
__global__ __launch_bounds__(256, 2) void mlp_split3(
    const float* __restrict__ xp,  const float* __restrict__ embp,
    const float* __restrict__ gW0p, const float* __restrict__ gb0p,
    const float* __restrict__ gW1p, const float* __restrict__ gb1p,
    const float* __restrict__ gW2p, const float* __restrict__ gb2p,
    const float* __restrict__ gW3p, const float* __restrict__ gb3p,
    float* __restrict__ out)
{
    __shared__ u16 sW1a[64 * STRW], sW1b[64 * STRW], sW1c[64 * STRW];
    __shared__ u16 sW2a[64 * STRW], sW2b[64 * STRW], sW2c[64 * STRW];
    __shared__ unsigned int scrH[4][16 * STRU];
    __shared__ unsigned int scrD[4][16 * STRU];
    __shared__ float sb1[64], sb2[64], sw3[64], sw0c[64], sE0[64], semb[16];

    const int tid = threadIdx.x;
    const int wave = tid >> 6, lane = tid & 63;
    const int q = lane >> 4, s = lane & 15;
    const int t = blockIdx.x, l = blockIdx.y;

    if (tid < 16) semb[tid] = embp[(t + 2) * 16 + tid];
    __syncthreads();

    {   // ---- stage W1/W2 as 3 split tiles each (hi/mid/lo bf16) ----
        const int row = tid >> 2, col = (tid & 3) * 16;
        const f32x4* g1 = (const f32x4*)(gW1p + (size_t)l * 4096) + tid * 4;
        const f32x4* g2 = (const f32x4*)(gW2p + (size_t)l * 4096) + tid * 4;
#pragma unroll
        for (int h = 0; h < 2; ++h) {
            f32x4 u0 = g1[h * 2], u1 = g1[h * 2 + 1];
            f32x4 v0 = g2[h * 2], v1 = g2[h * 2 + 1];
            unsigned int a[8], b[8], c[8], d[8], e[8], f[8];
#pragma unroll
            for (int i = 0; i < 4; ++i) {
                split3(u0[i], a[i], b[i], c[i]);
                split3(u1[i], a[4 + i], b[4 + i], c[4 + i]);
                split3(v0[i], d[i], e[i], f[i]);
                split3(v1[i], d[4 + i], e[4 + i], f[4 + i]);
            }
            uint4v pa, pb, pc, pd, pe, pf;
#pragma unroll
            for (int k = 0; k < 4; ++k) {
                pa[k] = packb(a[2 * k], a[2 * k + 1]);
                pb[k] = packb(b[2 * k], b[2 * k + 1]);
                pc[k] = packb(c[2 * k], c[2 * k + 1]);
                pd[k] = packb(d[2 * k], d[2 * k + 1]);
                pe[k] = packb(e[2 * k], e[2 * k + 1]);
                pf[k] = packb(f[2 * k], f[2 * k + 1]);
            }
            *(uint4v*)&sW1a[row * STRW + col + h * 8] = pa;
            *(uint4v*)&sW1b[row * STRW + col + h * 8] = pb;
            *(uint4v*)&sW1c[row * STRW + col + h * 8] = pc;
            *(uint4v*)&sW2a[row * STRW + col + h * 8] = pd;
            *(uint4v*)&sW2b[row * STRW + col + h * 8] = pe;
            *(uint4v*)&sW2c[row * STRW + col + h * 8] = pf;
        }
    }
    if (tid < 64) {   // E0 = b0 + W0[:, :16] @ emb[t+2]; w0c; small vectors
        const float* r = gW0p + (size_t)(l * 64 + tid) * 17;
        float acc = gb0p[l * 64 + tid];
#pragma unroll
        for (int e = 0; e < 16; e++) acc = fmaf(r[e], semb[e], acc);
        sE0[tid]  = acc;
        sw0c[tid] = r[16];
        sb1[tid]  = gb1p[l * 64 + tid];
        sb2[tid]  = gb2p[l * 64 + tid];
        sw3[tid]  = gW3p[l * 64 + tid];
    }
    __syncthreads();

    const float b3v = gb3p[l];
    const int bsmp = wave * 16 + s;
    const float xv = xp[(size_t)(bsmp * 1000 + t + 2) * 8 + l];
    const f32x4 zf = {0.f, 0.f, 0.f, 0.f};

    // ---- layer 0 -> 3-split B-frags (value + tangent), R5-verified layout ----
    short8 H0a[2], H0b[2], H0c[2], D0a[2], D0b[2], D0c[2];
#pragma unroll
    for (int kc = 0; kc < 2; ++kc) {
        f32x4 eA = *(const f32x4*)&sE0[kc * 32 + q * 8];
        f32x4 eB = *(const f32x4*)&sE0[kc * 32 + q * 8 + 4];
        f32x4 wA = *(const f32x4*)&sw0c[kc * 32 + q * 8];
        f32x4 wB = *(const f32x4*)&sw0c[kc * 32 + q * 8 + 4];
        unsigned int ha[8], hb[8], hc[8], da[8], db[8], dc[8];
#pragma unroll
        for (int i = 0; i < 8; ++i) {
            float w  = (i < 4) ? wA[i] : wB[i - 4];
            float e0 = (i < 4) ? eA[i] : eB[i - 4];
            float p  = fmaf(w, xv, e0);
            float hv = fmaxf(p, 0.2f * p);
            float dv = (p >= 0.f ? 1.f : 0.2f) * w;
            split3(hv, ha[i], hb[i], hc[i]);
            split3(dv, da[i], db[i], dc[i]);
        }
        uint4v A, B, C, D, E, F;
#pragma unroll
        for (int k = 0; k < 4; ++k) {
            A[k] = packb(ha[2 * k], ha[2 * k + 1]);
            B[k] = packb(hb[2 * k], hb[2 * k + 1]);
            C[k] = packb(hc[2 * k], hc[2 * k + 1]);
            D[k] = packb(da[2 * k], da[2 * k + 1]);
            E[k] = packb(db[2 * k], db[2 * k + 1]);
            F[k] = packb(dc[2 * k], dc[2 * k + 1]);
        }
        H0a[kc] = __builtin_bit_cast(short8, A);
        H0b[kc] = __builtin_bit_cast(short8, B);
        H0c[kc] = __builtin_bit_cast(short8, C);
        D0a[kc] = __builtin_bit_cast(short8, D);
        D0b[kc] = __builtin_bit_cast(short8, E);
        D0c[kc] = __builtin_bit_cast(short8, F);
    }

    // ---- layer 1: 6-term split GEMM (value + tangent), small terms first ----
    f32x4 aV[4], aT[4];
#pragma unroll
    for (int mb = 0; mb < 4; ++mb) { aV[mb] = zf; aT[mb] = zf; }
#pragma unroll
    for (int kc = 0; kc < 2; ++kc) {
#pragma unroll
        for (int mb = 0; mb < 4; ++mb) {
            const int wo = (mb * 16 + s) * STRW + kc * 32 + q * 8;
            short8 wa = __builtin_bit_cast(short8, *(const uint4v*)&sW1a[wo]);
            short8 wb = __builtin_bit_cast(short8, *(const uint4v*)&sW1b[wo]);
            short8 wc = __builtin_bit_cast(short8, *(const uint4v*)&sW1c[wo]);
            aV[mb] = __builtin_amdgcn_mfma_f32_16x16x32_bf16(wb, H0b[kc], aV[mb], 0, 0, 0);
            aV[mb] = __builtin_amdgcn_mfma_f32_16x16x32_bf16(wc, H0a[kc], aV[mb], 0, 0, 0);
            aV[mb] = __builtin_amdgcn_mfma_f32_16x16x32_bf16(wa, H0c[kc], aV[mb], 0, 0, 0);
            aV[mb] = __builtin_amdgcn_mfma_f32_16x16x32_bf16(wb, H0a[kc], aV[mb], 0, 0, 0);
            aV[mb] = __builtin_amdgcn_mfma_f32_16x16x32_bf16(wa, H0b[kc], aV[mb], 0, 0, 0);
            aV[mb] = __builtin_amdgcn_mfma_f32_16x16x32_bf16(wa, H0a[kc], aV[mb], 0, 0, 0);
            aT[mb] = __builtin_amdgcn_mfma_f32_16x16x32_bf16(wb, D0b[kc], aT[mb], 0, 0, 0);
            aT[mb] = __builtin_amdgcn_mfma_f32_16x16x32_bf16(wc, D0a[kc], aT[mb], 0, 0, 0);
            aT[mb] = __builtin_amdgcn_mfma_f32_16x16x32_bf16(wa, D0c[kc], aT[mb], 0, 0, 0);
            aT[mb] = __builtin_amdgcn_mfma_f32_16x16x32_bf16(wb, D0a[kc], aT[mb], 0, 0, 0);
            aT[mb] = __builtin_amdgcn_mfma_f32_16x16x32_bf16(wa, D0b[kc], aT[mb], 0, 0, 0);
            aT[mb] = __builtin_amdgcn_mfma_f32_16x16x32_bf16(wa, D0a[kc], aT[mb], 0, 0, 0);
        }
    }

    // ---- activation + 3-pass C->B-frag transform (per-wave scratch) ----
    uint2v hp1[4], hp2[4], hp3[4], dp1[4], dp2[4], dp3[4];
#pragma unroll
    for (int mb = 0; mb < 4; ++mb) {
        f32x4 b1v = *(const f32x4*)&sb1[mb * 16 + q * 4];
        unsigned int ha[4], hb[4], hc[4], da[4], db[4], dc[4];
#pragma unroll
        for (int i = 0; i < 4; ++i) {
            float p  = aV[mb][i] + b1v[i];
            float hv = fmaxf(p, 0.2f * p);
            float dv = (p >= 0.f ? 1.f : 0.2f) * aT[mb][i];
            split3(hv, ha[i], hb[i], hc[i]);
            split3(dv, da[i], db[i], dc[i]);
        }
        hp1[mb][0] = packb(ha[0], ha[1]); hp1[mb][1] = packb(ha[2], ha[3]);
        hp2[mb][0] = packb(hb[0], hb[1]); hp2[mb][1] = packb(hb[2], hb[3]);
        hp3[mb][0] = packb(hc[0], hc[1]); hp3[mb][1] = packb(hc[2], hc[3]);
        dp1[mb][0] = packb(da[0], da[1]); dp1[mb][1] = packb(da[2], da[3]);
        dp2[mb][0] = packb(db[0], db[1]); dp2[mb][1] = packb(db[2], db[3]);
        dp3[mb][0] = packb(dc[0], dc[1]); dp3[mb][1] = packb(dc[2], dc[3]);
    }
    unsigned int* mH = scrH[wave];
    unsigned int* mD = scrD[wave];
    short8 H1a[2], H1b[2], H1c[2], D1a[2], D1b[2], D1c[2];
    // pass 1 (hi)
#pragma unroll
    for (int mb = 0; mb < 4; ++mb) {
        *(uint2v*)&mH[s * STRU + mb * 8 + q * 2] = hp1[mb];
        *(uint2v*)&mD[s * STRU + mb * 8 + q * 2] = dp1[mb];
    }
    LDSFENCE();
#pragma unroll
    for (int kc = 0; kc < 2; ++kc) {
        H1a[kc] = __builtin_bit_cast(short8, *(const uint4v*)&mH[s * STRU + kc * 16 + q * 4]);
        D1a[kc] = __builtin_bit_cast(short8, *(const uint4v*)&mD[s * STRU + kc * 16 + q * 4]);
    }
    LDSFENCE();
    // pass 2 (mid)
#pragma unroll
    for (int mb = 0; mb < 4; ++mb) {
        *(uint2v*)&mH[s * STRU + mb * 8 + q * 2] = hp2[mb];
        *(uint2v*)&mD[s * STRU + mb * 8 + q * 2] = dp2[mb];
    }
    LDSFENCE();
#pragma unroll
    for (int kc = 0; kc < 2; ++kc) {
        H1b[kc] = __builtin_bit_cast(short8, *(const uint4v*)&mH[s * STRU + kc * 16 + q * 4]);
        D1b[kc] = __builtin_bit_cast(short8, *(const uint4v*)&mD[s * STRU + kc * 16 + q * 4]);
    }
    LDSFENCE();
    // pass 3 (lo)
#pragma unroll
    for (int mb = 0; mb < 4; ++mb) {
        *(uint2v*)&mH[s * STRU + mb * 8 + q * 2] = hp3[mb];
        *(uint2v*)&mD[s * STRU + mb * 8 + q * 2] = dp3[mb];
    }
    LDSFENCE();
#pragma unroll
    for (int kc = 0; kc < 2; ++kc) {
        H1c[kc] = __builtin_bit_cast(short8, *(const uint4v*)&mH[s * STRU + kc * 16 + q * 4]);
        D1c[kc] = __builtin_bit_cast(short8, *(const uint4v*)&mD[s * STRU + kc * 16 + q * 4]);
    }

    // ---- layer 2: 6-term split GEMM ----
#pragma unroll
    for (int mb = 0; mb < 4; ++mb) { aV[mb] = zf; aT[mb] = zf; }
#pragma unroll
    for (int kc = 0; kc < 2; ++kc) {
#pragma unroll
        for (int mb = 0; mb < 4; ++mb) {
            const int wo = (mb * 16 + s) * STRW + kc * 32 + q * 8;
            short8 wa = __builtin_bit_cast(short8, *(const uint4v*)&sW2a[wo]);
            short8 wb = __builtin_bit_cast(short8, *(const uint4v*)&sW2b[wo]);
            short8 wc = __builtin_bit_cast(short8, *(const uint4v*)&sW2c[wo]);
            aV[mb] = __builtin_amdgcn_mfma_f32_16x16x32_bf16(wb, H1b[kc], aV[mb], 0, 0, 0);
            aV[mb] = __builtin_amdgcn_mfma_f32_16x16x32_bf16(wc, H1a[kc], aV[mb], 0, 0, 0);
            aV[mb] = __builtin_amdgcn_mfma_f32_16x16x32_bf16(wa, H1c[kc], aV[mb], 0, 0, 0);
            aV[mb] = __builtin_amdgcn_mfma_f32_16x16x32_bf16(wb, H1a[kc], aV[mb], 0, 0, 0);
            aV[mb] = __builtin_amdgcn_mfma_f32_16x16x32_bf16(wa, H1b[kc], aV[mb], 0, 0, 0);
            aV[mb] = __builtin_amdgcn_mfma_f32_16x16x32_bf16(wa, H1a[kc], aV[mb], 0, 0, 0);
            aT[mb] = __builtin_amdgcn_mfma_f32_16x16x32_bf16(wb, D1b[kc], aT[mb], 0, 0, 0);
            aT[mb] = __builtin_amdgcn_mfma_f32_16x16x32_bf16(wc, D1a[kc], aT[mb], 0, 0, 0);
            aT[mb] = __builtin_amdgcn_mfma_f32_16x16x32_bf16(wa, D1c[kc], aT[mb], 0, 0, 0);
            aT[mb] = __builtin_amdgcn_mfma_f32_16x16x32_bf16(wb, D1a[kc], aT[mb], 0, 0, 0);
            aT[mb] = __builtin_amdgcn_mfma_f32_16x16x32_bf16(wa, D1b[kc], aT[mb], 0, 0, 0);
            aT[mb] = __builtin_amdgcn_mfma_f32_16x16x32_bf16(wa, D1a[kc], aT[mb], 0, 0, 0);
        }
    }

    // ---- layer 3 + quad butterfly + outputs (R5-verified) ----
    float rs = 0.f, js = 0.f;
#pragma unroll
    for (int mb = 0; mb < 4; ++mb) {
        f32x4 b2v = *(const f32x4*)&sb2[mb * 16 + q * 4];
        f32x4 w3v = *(const f32x4*)&sw3[mb * 16 + q * 4];
#pragma unroll
        for (int i = 0; i < 4; ++i) {
            float p = aV[mb][i] + b2v[i];
            float h = fmaxf(p, 0.2f * p);
            float d = (p >= 0.f ? 1.f : 0.2f) * aT[mb][i];
            rs = fmaf(w3v[i], h, rs);
            js = fmaf(w3v[i], d, js);
        }
    }
    rs += __shfl_xor(rs, 16, 64); rs += __shfl_xor(rs, 32, 64);
    js += __shfl_xor(js, 16, 64); js += __shfl_xor(js, 32, 64);
    if (lane < 16) {
        out[(size_t)(bsmp * LENT + t) * 8 + l] = rs + b3v;
        atomicAdd(&out[(size_t)NSAMP * 8 + (size_t)bsmp * LENT + t], __logf(fabsf(js)));
    }
}

extern "C" void kernel_launch(void* const* d_in, const int* in_sizes, int n_in,
                              void* d_out, int out_size, void* d_ws, size_t ws_size,
                              hipStream_t stream) {
    (void)in_sizes; (void)n_in; (void)out_size; (void)d_ws; (void)ws_size;
    // zero logdet region (accumulated via atomicAdd across the l-grid)
    hipMemsetAsync((char*)d_out + (size_t)NSAMP * 8 * sizeof(float), 0,
                   (size_t)NSAMP * sizeof(float), stream);
    mlp_split3<<<dim3(LENT, 8), 256, 0, stream>>>(
        (const float*)d_in[0], (const float*)d_in[1],
        (const float*)d_in[2], (const float*)d_in[3],
        (const float*)d_in[4], (const float*)d_in[5],
        (const float*)d_in[6], (const float*)d_in[7],
        (const float*)d_in[8], (const float*)d_in[9],
        (float*)d_out);
}